// Round 10
// baseline (176.466 us; speedup 1.0000x reference)
//
#include <hip/hip_runtime.h>

#define BB 8
#define CC 96
#define HH 224
#define WW 224

typedef _Float16 h2 __attribute__((ext_vector_type(2)));
__device__ __forceinline__ h2 u2h(unsigned u) { return __builtin_bit_cast(h2, u); }
__device__ __forceinline__ unsigned pkrtz(float a, float b) {
    return __builtin_bit_cast(unsigned, __builtin_amdgcn_cvt_pkrtz(a, b));
}

#if __has_builtin(__builtin_amdgcn_fdot2)
#define FDOT2(a, b, c) __builtin_amdgcn_fdot2((a), (b), (c), false)
#else
#define FDOT2(a, b, c) ((float)(a).x * (float)(b).x + (float)(a).y * (float)(b).y + (c))
#endif

// ---------------------------------------------------------------------------
// levels_fused: ONE block per (b,c). Levels 1+2 entirely in LDS. (unchanged)
// ---------------------------------------------------------------------------
__global__ __launch_bounds__(512, 4) void levels_fused(
    const float* __restrict__ x,
    float* __restrict__ c1,        // (B*C,4,56,56)
    float* __restrict__ c2,        // (B*C,4,28,28)
    const float* __restrict__ wt1, const float* __restrict__ ws1,
    const float* __restrict__ wt2, const float* __restrict__ ws2)
{
    const int bc = blockIdx.x, c = bc % CC;
    const int t = threadIdx.x;

    __shared__ unsigned s_c1[112 * 58];
    __shared__ unsigned s_sb1[4 * 60 * 31];
    __shared__ unsigned s_cur2[56 * 30];
    __shared__ unsigned s_sb2[4 * 32 * 17];
    __shared__ unsigned s_w2[240];

    for (int i = t; i < 4 * 60 * 31; i += 512) s_sb1[i] = 0;
    for (int i = t; i < 4 * 32 * 17; i += 512) s_sb2[i] = 0;

    if (t < 80) {
        int knl = t / 10;
        int par = t & 1, row = (t % 10) >> 1;
        int lvl = knl >> 2, s = knl & 3;
        const float* wt  = lvl ? wt2 : wt1;
        const float* wsc = lvl ? ws2 : ws1;
        float sc = 0.5f * wsc[c * 4 + s];
        float wv[5];
        #pragma unroll
        for (int j = 0; j < 5; ++j) wv[j] = wt[(c * 4 + s) * 25 + row * 5 + j] * sc;
        unsigned* dst = &s_w2[(knl * 2 + par) * 15 + row * 3];
        if (par == 0) {
            dst[0] = pkrtz(wv[0], wv[1]);
            dst[1] = pkrtz(wv[2], wv[3]);
            dst[2] = pkrtz(wv[4], 0.f);
        } else {
            dst[0] = pkrtz(0.f, wv[0]);
            dst[1] = pkrtz(wv[1], wv[2]);
            dst[2] = pkrtz(wv[3], wv[4]);
        }
    }

    const float* xp = x + (size_t)bc * HH * WW;
    for (int idx = t; idx < 112 * 56; idx += 512) {
        int r = idx / 56, g = idx % 56;
        const float* r0 = xp + (size_t)(2 * r) * WW + 4 * g;
        const float* r1 = r0 + WW;
        float4 a = *(const float4*)r0;
        float4 b = *(const float4*)r1;
        s_c1[r * 58 + g] = pkrtz(0.5f * (a.x + a.y + b.x + b.y),
                                 0.5f * (a.z + a.w + b.z + b.w));
    }
    __syncthreads();

    for (int idx = t; idx < 56 * 28; idx += 512) {
        int sr = idx / 28, sc2 = idx % 28;
        uint2 tp = *(const uint2*)&s_c1[(2 * sr) * 58 + 2 * sc2];
        uint2 bt = *(const uint2*)&s_c1[(2 * sr + 1) * 58 + 2 * sc2];
        h2 t0 = u2h(tp.x), t1 = u2h(tp.y), b0 = u2h(bt.x), b1 = u2h(bt.y);
        float P0 = (float)t0.x + (float)t0.y, M0 = (float)t0.x - (float)t0.y;
        float R0 = (float)b0.x + (float)b0.y, Q0 = (float)b0.x - (float)b0.y;
        float P1 = (float)t1.x + (float)t1.y, M1 = (float)t1.x - (float)t1.y;
        float R1 = (float)b1.x + (float)b1.y, Q1 = (float)b1.x - (float)b1.y;
        int o = (sr + 2) * 31 + (sc2 + 1);
        s_sb1[0 * 1860 + o] = pkrtz(P0 + R0, P1 + R1);
        s_sb1[1 * 1860 + o] = pkrtz(M0 + Q0, M1 + Q1);
        s_sb1[2 * 1860 + o] = pkrtz(P0 - R0, P1 - R1);
        s_sb1[3 * 1860 + o] = pkrtz(M0 - Q0, M1 - Q1);
        s_cur2[sr * 30 + sc2] = pkrtz(0.5f * (P0 + R0), 0.5f * (P1 + R1));
    }
    __syncthreads();

    if (t < 28 * 14) {
        int sr = t / 14, sc2 = t % 14;
        uint2 tp = *(const uint2*)&s_cur2[(2 * sr) * 30 + 2 * sc2];
        uint2 bt = *(const uint2*)&s_cur2[(2 * sr + 1) * 30 + 2 * sc2];
        h2 t0 = u2h(tp.x), t1 = u2h(tp.y), b0 = u2h(bt.x), b1 = u2h(bt.y);
        float P0 = (float)t0.x + (float)t0.y, M0 = (float)t0.x - (float)t0.y;
        float R0 = (float)b0.x + (float)b0.y, Q0 = (float)b0.x - (float)b0.y;
        float P1 = (float)t1.x + (float)t1.y, M1 = (float)t1.x - (float)t1.y;
        float R1 = (float)b1.x + (float)b1.y, Q1 = (float)b1.x - (float)b1.y;
        int o = (sr + 2) * 17 + (sc2 + 1);
        s_sb2[0 * 544 + o] = pkrtz(P0 + R0, P1 + R1);
        s_sb2[1 * 544 + o] = pkrtz(M0 + Q0, M1 + Q1);
        s_sb2[2 * 544 + o] = pkrtz(P0 - R0, P1 - R1);
        s_sb2[3 * 544 + o] = pkrtz(M0 - Q0, M1 - Q1);
    }

    {
        const int s = t >> 7, lane = t & 127;
        const int q = lane & 63, half = lane >> 6;
        if (q < 56) {
            const int par = q & 1, d0 = q >> 1, ps = half * 28;
            h2 w[5][3];
            {
                const unsigned* wp = &s_w2[(s * 2 + par) * 15];
                #pragma unroll
                for (int ki = 0; ki < 5; ++ki)
                    #pragma unroll
                    for (int m = 0; m < 3; ++m) w[ki][m] = u2h(wp[ki * 3 + m]);
            }
            float acc[28];
            #pragma unroll
            for (int r = 0; r < 28; ++r) acc[r] = 0.f;
            #pragma unroll
            for (int ri = 0; ri < 32; ++ri) {
                const unsigned* rp = &s_sb1[s * 1860 + (ps + ri) * 31 + d0];
                h2 g0 = u2h(rp[0]), g1 = u2h(rp[1]), g2 = u2h(rp[2]);
                #pragma unroll
                for (int ki = 0; ki < 5; ++ki) {
                    int r = ri - ki;
                    if (r >= 0 && r < 28)
                        acc[r] = FDOT2(g0, w[ki][0],
                                 FDOT2(g1, w[ki][1],
                                 FDOT2(g2, w[ki][2], acc[r])));
                }
            }
            const size_t ob = ((size_t)(bc * 4 + s) * 56 + ps) * 56 + q;
            #pragma unroll
            for (int r = 0; r < 28; ++r)
                c1[ob + (size_t)r * 56] = acc[r];
        }
    }
    __syncthreads();

    if (t < 112) {
        const int s = t / 28, q = t % 28;
        const int par = q & 1, d0 = q >> 1;
        h2 w[5][3];
        {
            const unsigned* wp = &s_w2[((4 + s) * 2 + par) * 15];
            #pragma unroll
            for (int ki = 0; ki < 5; ++ki)
                #pragma unroll
                for (int m = 0; m < 3; ++m) w[ki][m] = u2h(wp[ki * 3 + m]);
        }
        float acc[28];
        #pragma unroll
        for (int r = 0; r < 28; ++r) acc[r] = 0.f;
        #pragma unroll
        for (int ri = 0; ri < 32; ++ri) {
            const unsigned* rp = &s_sb2[s * 544 + ri * 17 + d0];
            h2 g0 = u2h(rp[0]), g1 = u2h(rp[1]), g2 = u2h(rp[2]);
            #pragma unroll
            for (int ki = 0; ki < 5; ++ki) {
                int r = ri - ki;
                if (r >= 0 && r < 28)
                    acc[r] = FDOT2(g0, w[ki][0],
                             FDOT2(g1, w[ki][1],
                             FDOT2(g2, w[ki][2], acc[r])));
            }
        }
        const size_t ob = (size_t)(bc * 4 + s) * 28 * 28 + q;
        #pragma unroll
        for (int r = 0; r < 28; ++r)
            c2[ob + (size_t)r * 28] = acc[r];
    }
}

// ---------------------------------------------------------------------------
// final_fused_v6: WAVE-SYNCHRONOUS. 64 threads = 1 wave per block, 32x32
// output tile (grid 7x7x768). No inter-wave barrier coupling; every phase
// maps exactly to 64 lanes:
//   base conv  : 32 cols x 2 row-halves = 64
//   subband conv: 4 bands x 16 cols     = 64
//   ihaar1     : 64 c1 positions (8x8x4 loads, 1 per thread)
//   combine    : 32 cols x 2 halves     = 64
// LDS ~9 KB -> ~17 blocks/CU, all independent waves.
// ---------------------------------------------------------------------------
__global__ __launch_bounds__(64) void final_fused_v6(
    const float* __restrict__ x,
    const float* __restrict__ bw,
    const float* __restrict__ bb,
    const float* __restrict__ bs,
    const float* __restrict__ wt0,
    const float* __restrict__ wsc0,
    const float* __restrict__ c1,   // (B*C,4,56,56)
    const float* __restrict__ c2,   // (B*C,4,28,28)
    float* __restrict__ out)
{
    const int bc = blockIdx.z, c = bc % CC;
    const int t = threadIdx.x;
    const int ox = 32 * blockIdx.x, oy = 32 * blockIdx.y;

    __shared__ unsigned s_x[40 * 22];     // fp16 x-tile (40x40), stride 22 dw
    __shared__ unsigned s_sb[4 * 20 * 11];// fp16 L0 subbands (20x20), stride 11
    __shared__ float s_rec1[16 * 17];
    __shared__ float s_rec2[8 * 9];
    __shared__ unsigned s_w2[150];        // [5 knl][2 par][5 row][3] h2
    _Float16* const s_cvh = reinterpret_cast<_Float16*>(s_x);  // overlay

    // ---- weights: folded, parity-padded half2 triplets ----
    if (t < 50) {
        int par = t & 1, row = (t >> 1) % 5, knl = t / 10;  // 0=base, 1..4=subband
        float wv[5];
        if (knl == 0) {
            float sc = bs[c];
            #pragma unroll
            for (int j = 0; j < 5; ++j) wv[j] = bw[c * 25 + row * 5 + j] * sc;
        } else {
            int s = knl - 1;
            float sc = 0.5f * wsc0[c * 4 + s];
            #pragma unroll
            for (int j = 0; j < 5; ++j) wv[j] = wt0[(c * 4 + s) * 25 + row * 5 + j] * sc;
        }
        unsigned* dst = &s_w2[((knl * 2 + par) * 5 + row) * 3];
        if (par == 0) {
            dst[0] = pkrtz(wv[0], wv[1]);
            dst[1] = pkrtz(wv[2], wv[3]);
            dst[2] = pkrtz(wv[4], 0.f);
        } else {
            dst[0] = pkrtz(0.f, wv[0]);
            dst[1] = pkrtz(wv[1], wv[2]);
            dst[2] = pkrtz(wv[3], wv[4]);
        }
    }

    // ---- coeff loads issued early (hide under staging) ----
    float c2v[4], c1v[4];
    if (t < 16) {
        const int p2 = t >> 2, q2 = t & 3;
        const size_t b2 = (((size_t)bc * 4) * 28 + 4 * blockIdx.y + p2) * 28
                        + 4 * blockIdx.x + q2;
        #pragma unroll
        for (int s = 0; s < 4; ++s) c2v[s] = c2[b2 + (size_t)s * 784];
    }
    const int p1 = t >> 3, q1 = t & 7;
    {
        const size_t b1 = (((size_t)bc * 4) * 56 + 8 * blockIdx.y + p1) * 56
                        + 8 * blockIdx.x + q1;
        #pragma unroll
        for (int s = 0; s < 4; ++s) c1v[s] = c1[b1 + (size_t)s * 3136];
    }

    // ---- stage 40x40 x-tile as packed fp16 ----
    const float* xp = x + (size_t)bc * HH * WW;
    const int gy0 = oy - 4, gx0 = ox - 4;
    #pragma unroll
    for (int it = 0; it < 7; ++it) {
        int idx = t + it * 64;
        if (idx < 400) {
            int r = idx / 10, j = idx % 10;
            int gr = gy0 + r, gc = gx0 + 4 * j;
            float4 v = make_float4(0.f, 0.f, 0.f, 0.f);
            if (gr >= 0 && gr < HH && gc >= 0 && gc + 3 < WW)
                v = *(const float4*)(xp + (size_t)gr * WW + gc);
            uint2 pp;
            pp.x = pkrtz(v.x, v.y);
            pp.y = pkrtz(v.z, v.w);
            *(uint2*)&s_x[r * 22 + 2 * j] = pp;
        }
    }

    // ---- ihaar level 2: c2 -> s_rec2 (8x8) ----
    if (t < 16) {
        const int p2 = t >> 2, q2 = t & 3;
        float ll = c2v[0], lh = c2v[1], hl = c2v[2], hh = c2v[3];
        float a  = 0.5f * (ll + lh + hl + hh);
        float b  = 0.5f * (ll - lh + hl - hh);
        float cv = 0.5f * (ll + lh - hl - hh);
        float d  = 0.5f * (ll - lh - hl + hh);
        float* rp = &s_rec2[(2 * p2) * 9 + 2 * q2];
        rp[0] = a; rp[1] = b; rp[9] = cv; rp[10] = d;
    }
    __syncthreads();

    // ---- butterfly: s_x -> s_sb (20x20 per band) ----
    #pragma unroll
    for (int it = 0; it < 4; ++it) {
        int idx = t + it * 64;
        if (idx < 200) {
            int sr = idx / 10, g = idx % 10;
            uint2 tp = *(const uint2*)&s_x[(2 * sr) * 22 + 2 * g];
            uint2 bt = *(const uint2*)&s_x[(2 * sr + 1) * 22 + 2 * g];
            h2 t0 = u2h(tp.x), t1 = u2h(tp.y), b0 = u2h(bt.x), b1 = u2h(bt.y);
            float P0 = (float)t0.x + (float)t0.y, M0 = (float)t0.x - (float)t0.y;
            float R0 = (float)b0.x + (float)b0.y, Q0 = (float)b0.x - (float)b0.y;
            float P1 = (float)t1.x + (float)t1.y, M1 = (float)t1.x - (float)t1.y;
            float R1 = (float)b1.x + (float)b1.y, Q1 = (float)b1.x - (float)b1.y;
            int o = sr * 11 + g;
            s_sb[0 * 220 + o] = pkrtz(P0 + R0, P1 + R1);
            s_sb[1 * 220 + o] = pkrtz(M0 + Q0, M1 + Q1);
            s_sb[2 * 220 + o] = pkrtz(P0 - R0, P1 - R1);
            s_sb[3 * 220 + o] = pkrtz(M0 - Q0, M1 - Q1);
        }
    }

    // ---- base conv: col q (0..31), half h; 16 outputs each ----
    const int qb = t & 31, hb = t >> 5;
    float bacc[16];
    {
        const int par = qb & 1, d0 = (qb + 2) >> 1;
        h2 w[5][3];
        {
            const unsigned* wp = &s_w2[(par * 5) * 3];
            #pragma unroll
            for (int ki = 0; ki < 5; ++ki)
                #pragma unroll
                for (int m = 0; m < 3; ++m) w[ki][m] = u2h(wp[ki * 3 + m]);
        }
        #pragma unroll
        for (int r = 0; r < 16; ++r) bacc[r] = 0.f;
        #pragma unroll
        for (int ri = 0; ri < 20; ++ri) {
            const unsigned* rp = &s_x[(hb * 16 + ri + 2) * 22 + d0];
            h2 g0 = u2h(rp[0]), g1 = u2h(rp[1]), g2 = u2h(rp[2]);
            #pragma unroll
            for (int ki = 0; ki < 5; ++ki) {
                int r = ri - ki;
                if (r >= 0 && r < 16)
                    bacc[r] = FDOT2(g0, w[ki][0],
                              FDOT2(g1, w[ki][1],
                              FDOT2(g2, w[ki][2], bacc[r])));
            }
        }
    }

    // ---- ihaar level 1: (c1 with LL += rec2) -> s_rec1 (16x16) ----
    {
        float ll = c1v[0] + s_rec2[p1 * 9 + q1];
        float lh = c1v[1], hl = c1v[2], hh = c1v[3];
        float a  = 0.5f * (ll + lh + hl + hh);
        float b  = 0.5f * (ll - lh + hl - hh);
        float cv = 0.5f * (ll + lh - hl - hh);
        float d  = 0.5f * (ll - lh - hl + hh);
        float* rp = &s_rec1[(2 * p1) * 17 + 2 * q1];
        rp[0] = a; rp[1] = b; rp[17] = cv; rp[18] = d;
    }
    __syncthreads();

    // ---- subband conv: band s = t>>4, col q = t&15; -> s_cvh (overlay s_x) ----
    {
        const int s = t >> 4, q = t & 15;
        const int par = q & 1, d0 = q >> 1;
        h2 w[5][3];
        {
            const unsigned* wp = &s_w2[(((1 + s) * 2 + par) * 5) * 3];
            #pragma unroll
            for (int ki = 0; ki < 5; ++ki)
                #pragma unroll
                for (int m = 0; m < 3; ++m) w[ki][m] = u2h(wp[ki * 3 + m]);
        }
        float acc[16];
        #pragma unroll
        for (int r = 0; r < 16; ++r) acc[r] = 0.f;
        #pragma unroll
        for (int ri = 0; ri < 20; ++ri) {
            const unsigned* rp = &s_sb[s * 220 + ri * 11 + d0];
            h2 g0 = u2h(rp[0]), g1 = u2h(rp[1]), g2 = u2h(rp[2]);
            #pragma unroll
            for (int ki = 0; ki < 5; ++ki) {
                int r = ri - ki;
                if (r >= 0 && r < 16)
                    acc[r] = FDOT2(g0, w[ki][0],
                             FDOT2(g1, w[ki][1],
                             FDOT2(g2, w[ki][2], acc[r])));
            }
        }
        #pragma unroll
        for (int r = 0; r < 16; ++r)
            s_cvh[(s * 16 + r) * 18 + q] = (_Float16)acc[r];
    }
    __syncthreads();

    // ---- combine: ihaar level 0 + base + store ----
    {
        const float bbv = bb[c];
        const int qs = qb >> 1;
        const float sx = (qb & 1) ? -1.f : 1.f;
        float* op = out + ((size_t)bc * HH + oy + hb * 16) * WW + ox + qb;
        #pragma unroll
        for (int j = 0; j < 8; ++j) {
            const int p = hb * 8 + j;
            float ll = (float)s_cvh[(0 * 16 + p) * 18 + qs] + s_rec1[p * 17 + qs];
            float lh = (float)s_cvh[(1 * 16 + p) * 18 + qs];
            float hl = (float)s_cvh[(2 * 16 + p) * 18 + qs];
            float hh = (float)s_cvh[(3 * 16 + p) * 18 + qs];
            float e0 = ll + sx * lh;
            float e1 = hl + sx * hh;
            float top = 0.5f * (e0 + e1);
            float bot = 0.5f * (e0 - e1);
            op[(size_t)(2 * j) * WW]     = bacc[2 * j]     + bbv + top;
            op[(size_t)(2 * j + 1) * WW] = bacc[2 * j + 1] + bbv + bot;
        }
    }
}

extern "C" void kernel_launch(void* const* d_in, const int* in_sizes, int n_in,
                              void* d_out, int out_size, void* d_ws, size_t ws_size,
                              hipStream_t stream) {
    const float* x          = (const float*)d_in[0];
    const float* base_w     = (const float*)d_in[1];
    const float* base_b     = (const float*)d_in[2];
    const float* base_scale = (const float*)d_in[3];
    const float* wconv_w    = (const float*)d_in[4]; // (3, 384, 25)
    const float* wscale     = (const float*)d_in[5]; // (3, 384)
    float* out = (float*)d_out;
    float* ws  = (float*)d_ws;

    const size_t n1 = (size_t)BB * CC * 4 * 56 * 56;   // coeffs1

    float* coeffs1 = ws;
    float* coeffs2 = coeffs1 + n1;

    const int z = BB * CC;

    // levels 1+2 fully fused, one block per (b,c)
    levels_fused<<<z, 512, 0, stream>>>(
        x, coeffs1, coeffs2,
        wconv_w + 1 * 384 * 25, wscale + 1 * 384,
        wconv_w + 2 * 384 * 25, wscale + 2 * 384);
    // final: wave-synchronous 32x32 tiles
    final_fused_v6<<<dim3(7, 7, z), 64, 0, stream>>>(
        x, base_w, base_b, base_scale,
        wconv_w + 0 * 384 * 25, wscale + 0 * 384, coeffs1, coeffs2, out);
}